// Round 1
// baseline (1454.839 us; speedup 1.0000x reference)
//
#include <hip/hip_runtime.h>
#include <math.h>

// ---------------------------------------------------------------------------
// GAT 3-layer + pooling. Structure:
//  1. Build CSR (by dst) on-device: deg histogram -> 1-block scan -> fill.
//  2. Per layer: fp32 tiled GEMM (feat = x @ W), attn logit dots (el/er),
//     node-centric online-softmax aggregation (1 wave per (node, head),
//     fused residual+bias+ELU epilogue).
//  3. Head-mean -> local_feat, graph pooling (atomics), tiny final MLP.
// ---------------------------------------------------------------------------

// ----------------------------- CSR construction ---------------------------

__global__ __launch_bounds__(256) void deg_kernel(const int* __restrict__ dst,
                                                  int* __restrict__ deg, int E) {
    int e = blockIdx.x * 256 + threadIdx.x;
    if (e < E) atomicAdd(&deg[dst[e]], 1);
}

__global__ __launch_bounds__(1024) void scan_kernel(const int* __restrict__ deg,
                                                    int* __restrict__ row_off, int n) {
    __shared__ int sums[1024];
    int t = threadIdx.x;
    int CH = (n + 1023) >> 10;     // elements per thread chunk
    int base = t * CH;
    int s = 0;
    for (int i = 0; i < CH; ++i) { int idx = base + i; if (idx < n) s += deg[idx]; }
    sums[t] = s;
    __syncthreads();
    // Hillis-Steele inclusive scan over 1024 partials
    for (int off = 1; off < 1024; off <<= 1) {
        int v = (t >= off) ? sums[t - off] : 0;
        __syncthreads();
        sums[t] += v;
        __syncthreads();
    }
    int run = (t == 0) ? 0 : sums[t - 1];   // exclusive prefix of this chunk
    for (int i = 0; i < CH; ++i) {
        int idx = base + i;
        if (idx < n) { row_off[idx] = run; run += deg[idx]; }
    }
    if (t == 1023) row_off[n] = run;        // total edge count
}

__global__ __launch_bounds__(256) void fill_kernel(const int* __restrict__ src,
                                                   const int* __restrict__ dst,
                                                   const int* __restrict__ row_off,
                                                   int* __restrict__ fill,
                                                   int* __restrict__ csr_src, int E) {
    int e = blockIdx.x * 256 + threadIdx.x;
    if (e < E) {
        int d = dst[e];
        int pos = row_off[d] + atomicAdd(&fill[d], 1);
        csr_src[pos] = src[e];
    }
}

// ------------------------------- fp32 GEMM ---------------------------------
// C[M,N] = A[M,K] @ B[K,N].  BM=BN=64, BK=16, 256 threads, 4x4 per thread.
// K must be a multiple of 16, N a multiple of 64 (holds: K in {128,512},
// N in {512,768}). M edge (20000 % 64 == 32) guarded.

__global__ __launch_bounds__(256) void gemm_kernel(const float* __restrict__ A,
                                                   const float* __restrict__ B,
                                                   float* __restrict__ C,
                                                   int M, int N, int K) {
    __shared__ float As[16][64 + 4];
    __shared__ float Bs[16][64 + 4];
    int t = threadIdx.x;
    int bm = blockIdx.y * 64;
    int bn = blockIdx.x * 64;
    int ty = t >> 4, tx = t & 15;
    int arow = t >> 2;          // 0..63
    int ak   = (t & 3) * 4;     // 0,4,8,12
    int brow = t >> 4;          // 0..15
    int bcol = (t & 15) * 4;    // 0..60

    float acc[4][4];
#pragma unroll
    for (int i = 0; i < 4; ++i)
#pragma unroll
        for (int j = 0; j < 4; ++j) acc[i][j] = 0.f;

    for (int k0 = 0; k0 < K; k0 += 16) {
        float4 av = make_float4(0.f, 0.f, 0.f, 0.f);
        int gr = bm + arow;
        if (gr < M) av = *(const float4*)&A[(size_t)gr * K + k0 + ak];
        As[ak + 0][arow] = av.x;
        As[ak + 1][arow] = av.y;
        As[ak + 2][arow] = av.z;
        As[ak + 3][arow] = av.w;
        float4 bv = *(const float4*)&B[(size_t)(k0 + brow) * N + bn + bcol];
        *(float4*)&Bs[brow][bcol] = bv;
        __syncthreads();
#pragma unroll
        for (int k = 0; k < 16; ++k) {
            float4 a = *(const float4*)&As[k][ty * 4];
            float4 b = *(const float4*)&Bs[k][tx * 4];
            float ar[4] = {a.x, a.y, a.z, a.w};
            float br[4] = {b.x, b.y, b.z, b.w};
#pragma unroll
            for (int i = 0; i < 4; ++i)
#pragma unroll
                for (int j = 0; j < 4; ++j) acc[i][j] += ar[i] * br[j];
        }
        __syncthreads();
    }
#pragma unroll
    for (int i = 0; i < 4; ++i) {
        int gr = bm + ty * 4 + i;
        if (gr < M) {
            float4 o = make_float4(acc[i][0], acc[i][1], acc[i][2], acc[i][3]);
            *(float4*)&C[(size_t)gr * N + bn + tx * 4] = o;
        }
    }
}

// --------------------------- attention logits ------------------------------
// el[v,h] = dot(feat[v,h,:], al[h,:]);  er likewise. One wave per (node,head).

__global__ void attn_logits_kernel(const float* __restrict__ feat,
                                   const float* __restrict__ al,
                                   const float* __restrict__ ar,
                                   float* __restrict__ el, float* __restrict__ er,
                                   int H) {
    int v = blockIdx.x;
    int h = threadIdx.y;
    int lane = threadIdx.x;
    const float* f = feat + (size_t)v * H * 128 + h * 128;
    float f0 = f[lane], f1 = f[lane + 64];
    float sl = f0 * al[h * 128 + lane] + f1 * al[h * 128 + lane + 64];
    float sr = f0 * ar[h * 128 + lane] + f1 * ar[h * 128 + lane + 64];
#pragma unroll
    for (int off = 32; off > 0; off >>= 1) {
        sl += __shfl_down(sl, off, 64);
        sr += __shfl_down(sr, off, 64);
    }
    if (lane == 0) { el[v * H + h] = sl; er[v * H + h] = sr; }
}

// ----------------------- online-softmax aggregation ------------------------
// One wave per (node, head); lane holds feature channels 2*lane, 2*lane+1.
// out[v,h,:] = softmax_over_in_edges(leaky(el[src]+er[v])) . feat[src,h,:]
//              (+ res) (+ bias) (elu if act)

__global__ void gat_aggregate_kernel(const float* __restrict__ feat,
                                     const float* __restrict__ el,
                                     const float* __restrict__ er,
                                     const int* __restrict__ row_off,
                                     const int* __restrict__ csr_src,
                                     const float* __restrict__ res,
                                     const float* __restrict__ bias,
                                     float* __restrict__ out,
                                     int H, int act_elu) {
    int v = blockIdx.x;
    int h = threadIdx.y;
    int lane = threadIdx.x;
    int HD = H * 128;
    float er_v = er[v * H + h];
    int beg = row_off[v], end = row_off[v + 1];
    float m = -INFINITY, l = 0.f, acc0 = 0.f, acc1 = 0.f;
    for (int e = beg; e < end; ++e) {
        int s = csr_src[e];
        float logit = el[s * H + h] + er_v;
        logit = (logit >= 0.f) ? logit : 0.2f * logit;   // leaky_relu 0.2
        float m_new = fmaxf(m, logit);
        float scale = expf(m - m_new);   // first iter: exp(-inf)=0
        float w = expf(logit - m_new);
        float2 f = *(const float2*)&feat[(size_t)s * HD + h * 128 + lane * 2];
        l = l * scale + w;
        acc0 = acc0 * scale + w * f.x;
        acc1 = acc1 * scale + w * f.y;
        m = m_new;
    }
    float inv = 1.f / fmaxf(l, 1e-9f);
    float o0 = acc0 * inv, o1 = acc1 * inv;
    size_t base = (size_t)v * HD + h * 128 + lane * 2;
    if (res) { o0 += res[base]; o1 += res[base + 1]; }
    o0 += bias[h * 128 + lane * 2];
    o1 += bias[h * 128 + lane * 2 + 1];
    if (act_elu) {
        o0 = (o0 > 0.f) ? o0 : expm1f(o0);
        o1 = (o1 > 0.f) ? o1 : expm1f(o1);
    }
    out[base] = o0;
    out[base + 1] = o1;
}

// ------------------------- head-mean + graph pooling -----------------------

__global__ void mean_pool_kernel(const float* __restrict__ x3,
                                 const int* __restrict__ gid,
                                 float* __restrict__ local,
                                 float* __restrict__ pooled,
                                 float* __restrict__ cnt) {
    int v = blockIdx.x;
    int d = threadIdx.x;   // 128 threads
    const float* p = x3 + (size_t)v * 768;
    float s = 0.f;
#pragma unroll
    for (int h = 0; h < 6; ++h) s += p[h * 128 + d];
    s *= (1.f / 6.f);
    local[(size_t)v * 128 + d] = s;
    int g = gid[v];
    atomicAdd(&pooled[g * 128 + d], s);
    if (d == 0) atomicAdd(&cnt[g], 1.0f);
}

__global__ void final_mlp_kernel(const float* __restrict__ pooled,
                                 const float* __restrict__ cnt,
                                 const float* __restrict__ Wm,
                                 const float* __restrict__ bm,
                                 float* __restrict__ gout) {
    int g = blockIdx.x;
    int j = threadIdx.x;   // 128
    __shared__ float p[128];
    float c = fmaxf(cnt[g], 1.0f);
    p[j] = pooled[g * 128 + j] / c;
    __syncthreads();
    float s = 0.f;
#pragma unroll 16
    for (int k = 0; k < 128; ++k) s += p[k] * Wm[k * 128 + j];
    gout[g * 128 + j] = s + bm[j];
}

// --------------------------------- driver ----------------------------------

extern "C" void kernel_launch(void* const* d_in, const int* in_sizes, int n_in,
                              void* d_out, int out_size, void* d_ws, size_t ws_size,
                              hipStream_t stream) {
    const float* h     = (const float*)d_in[0];
    const int*   src   = (const int*)d_in[2];
    const int*   dst   = (const int*)d_in[3];
    const int*   gid   = (const int*)d_in[4];
    const float* W0    = (const float*)d_in[5];
    const float* al0   = (const float*)d_in[6];
    const float* ar0   = (const float*)d_in[7];
    const float* b0    = (const float*)d_in[8];
    const float* W1    = (const float*)d_in[9];
    const float* al1   = (const float*)d_in[10];
    const float* ar1   = (const float*)d_in[11];
    const float* b1    = (const float*)d_in[12];
    const float* W2    = (const float*)d_in[13];
    const float* al2   = (const float*)d_in[14];
    const float* ar2   = (const float*)d_in[15];
    const float* b2    = (const float*)d_in[16];
    const float* resW2 = (const float*)d_in[17];
    const float* Wm    = (const float*)d_in[18];
    const float* bm    = (const float*)d_in[19];

    const int n = in_sizes[0] / 128;   // 20000
    const int E = in_sizes[2];         // 320000

    // workspace carve (256B aligned)
    size_t off = 0;
    auto take = [&](size_t bytes) -> void* {
        void* p = (char*)d_ws + off;
        off = (off + bytes + 255) & ~(size_t)255;
        return p;
    };
    float* A   = (float*)take((size_t)n * 768 * 4);   // gemm outputs (feat)
    float* Bb  = (float*)take((size_t)n * 768 * 4);   // x1 / res2 / x3
    float* Cc  = (float*)take((size_t)n * 768 * 4);   // x2
    float* el  = (float*)take((size_t)n * 6 * 4);
    float* er  = (float*)take((size_t)n * 6 * 4);
    int* deg     = (int*)take((size_t)n * 4);
    int* row_off = (int*)take((size_t)(n + 1) * 4);
    int* fillc   = (int*)take((size_t)n * 4);
    int* csr_src = (int*)take((size_t)E * 4);
    float* pooled = (float*)take(64 * 128 * 4);
    float* cnt    = (float*)take(64 * 4);

    float* out_local  = (float*)d_out;                 // [n,128]
    float* out_global = (float*)d_out + (size_t)n * 128;  // [64,128]

    // --- CSR build ---
    hipMemsetAsync(deg, 0, (size_t)n * 4, stream);
    hipMemsetAsync(fillc, 0, (size_t)n * 4, stream);
    hipMemsetAsync(pooled, 0, 64 * 128 * 4, stream);
    hipMemsetAsync(cnt, 0, 64 * 4, stream);
    deg_kernel<<<(E + 255) / 256, 256, 0, stream>>>(dst, deg, E);
    scan_kernel<<<1, 1024, 0, stream>>>(deg, row_off, n);
    fill_kernel<<<(E + 255) / 256, 256, 0, stream>>>(src, dst, row_off, fillc, csr_src, E);

    int gy = (n + 63) / 64;

    // --- layer 0: in=h[n,128], W0[128,512], H=4, no res, elu ---
    gemm_kernel<<<dim3(512 / 64, gy), 256, 0, stream>>>(h, W0, A, n, 512, 128);
    attn_logits_kernel<<<n, dim3(64, 4), 0, stream>>>(A, al0, ar0, el, er, 4);
    gat_aggregate_kernel<<<n, dim3(64, 4), 0, stream>>>(A, el, er, row_off, csr_src,
                                                        nullptr, b0, Bb, 4, 1);
    // --- layer 1: x1=Bb[n,512], W1[512,512], H=4, identity res, elu ---
    gemm_kernel<<<dim3(512 / 64, gy), 256, 0, stream>>>(Bb, W1, A, n, 512, 512);
    attn_logits_kernel<<<n, dim3(64, 4), 0, stream>>>(A, al1, ar1, el, er, 4);
    gat_aggregate_kernel<<<n, dim3(64, 4), 0, stream>>>(A, el, er, row_off, csr_src,
                                                        Bb, b1, Cc, 4, 1);
    // --- layer 2: x2=Cc[n,512], W2[512,768], H=6, res = x2@resW2, no act ---
    gemm_kernel<<<dim3(768 / 64, gy), 256, 0, stream>>>(Cc, W2, A, n, 768, 512);
    attn_logits_kernel<<<n, dim3(64, 6), 0, stream>>>(A, al2, ar2, el, er, 6);
    gemm_kernel<<<dim3(768 / 64, gy), 256, 0, stream>>>(Cc, resW2, Bb, n, 768, 512);
    gat_aggregate_kernel<<<n, dim3(64, 6), 0, stream>>>(A, el, er, row_off, csr_src,
                                                        Bb, b2, Bb, 6, 0);
    // --- head mean + pooling + final MLP ---
    mean_pool_kernel<<<n, 128, 0, stream>>>(Bb, gid, out_local, pooled, cnt);
    final_mlp_kernel<<<64, 128, 0, stream>>>(pooled, cnt, Wm, bm, out_global);
}

// Round 2
// 988.957 us; speedup vs baseline: 1.4711x; 1.4711x over previous
//
#include <hip/hip_runtime.h>
#include <math.h>

// ---------------------------------------------------------------------------
// GAT 3-layer + pooling, fp16-MFMA edition.
//  - All GEMMs: fp16 inputs (converted on device), fp32 accumulate via
//    v_mfma_f32_16x16x32_f16, 128x128x32 tiles, global_load_lds staging.
//  - Activations / feat stored fp16 -> halves edge-gather traffic.
//  - CSR by dst built on device; node-centric 2-pass softmax aggregation.
// ---------------------------------------------------------------------------

typedef _Float16 f16;
typedef __attribute__((ext_vector_type(8))) _Float16 half8;
typedef __attribute__((ext_vector_type(4))) _Float16 half4;
typedef __attribute__((ext_vector_type(2))) _Float16 half2v;
typedef __attribute__((ext_vector_type(4))) float float4v;

#define M_PAD 20096   // 20000 rounded up to 128

__device__ inline void gload_lds16(const void* g, void* l) {
    __builtin_amdgcn_global_load_lds((const __attribute__((address_space(1))) unsigned*)g,
                                     (__attribute__((address_space(3))) unsigned*)l,
                                     16, 0, 0);
}

// ----------------------------- CSR construction ---------------------------

__global__ __launch_bounds__(256) void deg_kernel(const int* __restrict__ dst,
                                                  int* __restrict__ deg, int E) {
    int e = blockIdx.x * 256 + threadIdx.x;
    if (e < E) atomicAdd(&deg[dst[e]], 1);
}

__global__ __launch_bounds__(1024) void scan_kernel(const int* __restrict__ deg,
                                                    int* __restrict__ row_off, int n) {
    __shared__ int sums[1024];
    int t = threadIdx.x;
    int CH = (n + 1023) >> 10;
    int base = t * CH;
    int s = 0;
    for (int i = 0; i < CH; ++i) { int idx = base + i; if (idx < n) s += deg[idx]; }
    sums[t] = s;
    __syncthreads();
    for (int off = 1; off < 1024; off <<= 1) {
        int v = (t >= off) ? sums[t - off] : 0;
        __syncthreads();
        sums[t] += v;
        __syncthreads();
    }
    int run = (t == 0) ? 0 : sums[t - 1];
    for (int i = 0; i < CH; ++i) {
        int idx = base + i;
        if (idx < n) { row_off[idx] = run; run += deg[idx]; }
    }
    if (t == 1023) row_off[n] = run;
}

__global__ __launch_bounds__(256) void fill_kernel(const int* __restrict__ src,
                                                   const int* __restrict__ dst,
                                                   const int* __restrict__ row_off,
                                                   int* __restrict__ fill,
                                                   int* __restrict__ csr_src, int E) {
    int e = blockIdx.x * 256 + threadIdx.x;
    if (e < E) {
        int d = dst[e];
        int pos = row_off[d] + atomicAdd(&fill[d], 1);
        csr_src[pos] = src[e];
    }
}

// ------------------------------ converts -----------------------------------

// fp32 -> fp16 with zero pad past n_valid (n_valid multiple of 4)
__global__ __launch_bounds__(256) void cvt_pad_kernel(const float* __restrict__ x,
                                                      f16* __restrict__ y,
                                                      long n_valid, long n_total) {
    long i = ((long)blockIdx.x * 256 + threadIdx.x) * 4;
    if (i >= n_total) return;
    float4 v = make_float4(0.f, 0.f, 0.f, 0.f);
    if (i < n_valid) v = *(const float4*)&x[i];
    half4 o; o[0] = (f16)v.x; o[1] = (f16)v.y; o[2] = (f16)v.z; o[3] = (f16)v.w;
    *(half4*)&y[i] = o;
}

// Wt[n][k] = (f16) W[k][n].  K,N multiples of 32.  block (32,8)
__global__ __launch_bounds__(256) void transpose_cvt_kernel(const float* __restrict__ W,
                                                            f16* __restrict__ Wt,
                                                            int K, int N) {
    __shared__ float tile[32][33];
    int n0 = blockIdx.x * 32, k0 = blockIdx.y * 32;
    int tx = threadIdx.x, ty = threadIdx.y;
#pragma unroll
    for (int i = 0; i < 32; i += 8)
        tile[ty + i][tx] = W[(size_t)(k0 + ty + i) * N + n0 + tx];
    __syncthreads();
#pragma unroll
    for (int i = 0; i < 32; i += 8)
        Wt[(size_t)(n0 + ty + i) * K + k0 + tx] = (f16)tile[tx][ty + i];
}

// ------------------------------ fp16 MFMA GEMM -----------------------------
// C[M,N](f16) = A[M,K](f16) @ Bt[N,K](f16)^T, fp32 accum.
// M multiple of 128 (padded), N multiple of 128, K multiple of 32.
// 256 thr = 4 waves; wave -> 64x64 quadrant; 16x16x32 MFMA with swapped
// operands so lane's 4 acc regs are 4 consecutive columns (8B f16 store).

__global__ __launch_bounds__(256) void gemm16_kernel(const f16* __restrict__ A,
                                                     const f16* __restrict__ Bt,
                                                     f16* __restrict__ C,
                                                     int N, int K) {
    __shared__ f16 As[128 * 32];
    __shared__ f16 Bs[128 * 32];
    int t = threadIdx.x;
    int w = t >> 6;
    int l = t & 63;
    size_t bm = (size_t)blockIdx.y * 128;
    int bn = blockIdx.x * 128;
    int wm = (w & 1) * 64;
    int wn = (w >> 1) * 64;

    int srow = t >> 2;            // 0..63
    int scol = (t & 3) * 8;       // f16 offset 0,8,16,24
    const f16* ag0 = A + (bm + srow) * K + scol;
    const f16* ag1 = A + (bm + 64 + srow) * K + scol;
    const f16* bg0 = Bt + (size_t)(bn + srow) * K + scol;
    const f16* bg1 = Bt + (size_t)(bn + 64 + srow) * K + scol;
    f16* al0 = As + t * 8;
    f16* al1 = As + 2048 + t * 8;
    f16* bl0 = Bs + t * 8;
    f16* bl1 = Bs + 2048 + t * 8;

    float4v acc[4][4];
#pragma unroll
    for (int i = 0; i < 4; ++i)
#pragma unroll
        for (int j = 0; j < 4; ++j) acc[i][j] = (float4v)(0.f);

    int ml = l & 15, q = l >> 4;
    const f16* ap = As + (wm + ml) * 32 + q * 8;
    const f16* bp = Bs + (wn + ml) * 32 + q * 8;

    for (int k0 = 0; k0 < K; k0 += 32) {
        gload_lds16(ag0 + k0, al0);
        gload_lds16(ag1 + k0, al1);
        gload_lds16(bg0 + k0, bl0);
        gload_lds16(bg1 + k0, bl1);
        __syncthreads();
        half8 af[4], bf[4];
#pragma unroll
        for (int mt = 0; mt < 4; ++mt) af[mt] = *(const half8*)(ap + mt * 16 * 32);
#pragma unroll
        for (int nt = 0; nt < 4; ++nt) bf[nt] = *(const half8*)(bp + nt * 16 * 32);
#pragma unroll
        for (int mt = 0; mt < 4; ++mt)
#pragma unroll
            for (int nt = 0; nt < 4; ++nt)
                acc[mt][nt] = __builtin_amdgcn_mfma_f32_16x16x32_f16(bf[nt], af[mt],
                                                                     acc[mt][nt], 0, 0, 0);
        __syncthreads();
    }
    // lane l, tile (mt,nt), reg r -> C[bm+wm+mt*16+ml][bn+wn+nt*16+q*4+r]
#pragma unroll
    for (int mt = 0; mt < 4; ++mt) {
        size_t row = bm + wm + mt * 16 + ml;
#pragma unroll
        for (int nt = 0; nt < 4; ++nt) {
            half4 hv;
#pragma unroll
            for (int r = 0; r < 4; ++r) hv[r] = (f16)acc[mt][nt][r];
            *(half4*)&C[row * N + bn + wn + nt * 16 + q * 4] = hv;
        }
    }
}

// --------------------------- attention logits ------------------------------

__global__ void attn_logits_kernel(const f16* __restrict__ feat,
                                   const float* __restrict__ al,
                                   const float* __restrict__ ar,
                                   float* __restrict__ el, float* __restrict__ er,
                                   int H) {
    int v = blockIdx.x;
    int h = threadIdx.y;
    int lane = threadIdx.x;
    half2v f2 = *(const half2v*)&feat[(size_t)v * H * 128 + h * 128 + 2 * lane];
    float f0 = (float)f2[0], f1 = (float)f2[1];
    float sl = f0 * al[h * 128 + 2 * lane] + f1 * al[h * 128 + 2 * lane + 1];
    float sr = f0 * ar[h * 128 + 2 * lane] + f1 * ar[h * 128 + 2 * lane + 1];
#pragma unroll
    for (int off = 32; off > 0; off >>= 1) {
        sl += __shfl_down(sl, off, 64);
        sr += __shfl_down(sr, off, 64);
    }
    if (lane == 0) { el[v * H + h] = sl; er[v * H + h] = sr; }
}

// ----------------------- softmax aggregation (2-pass) ----------------------
// One wave per (node, head); lane holds channels 2*lane, 2*lane+1.

__global__ void gat_aggregate_kernel(const f16* __restrict__ feat,
                                     const float* __restrict__ el,
                                     const float* __restrict__ er,
                                     const int* __restrict__ row_off,
                                     const int* __restrict__ csr_src,
                                     const f16* __restrict__ res,
                                     const float* __restrict__ bias,
                                     f16* __restrict__ out16,
                                     float* __restrict__ out32,
                                     int H, int act_elu) {
    int v = blockIdx.x;
    int h = threadIdx.y;
    int lane = threadIdx.x;
    int HD = H * 128;
    float er_v = er[v * H + h];
    int beg = row_off[v], end = row_off[v + 1];

    float m = -INFINITY;
    for (int e = beg; e < end; ++e) {
        float lg = el[csr_src[e] * H + h] + er_v;
        lg = (lg >= 0.f) ? lg : 0.2f * lg;
        m = fmaxf(m, lg);
    }
    if (!(m > -INFINITY)) m = 0.f;

    float acc0 = 0.f, acc1 = 0.f, lsum = 0.f;
    for (int e = beg; e < end; ++e) {
        int s = csr_src[e];
        float lg = el[s * H + h] + er_v;
        lg = (lg >= 0.f) ? lg : 0.2f * lg;
        float wgt = __expf(lg - m);
        half2v f2 = *(const half2v*)&feat[(size_t)s * HD + h * 128 + lane * 2];
        lsum += wgt;
        acc0 += wgt * (float)f2[0];
        acc1 += wgt * (float)f2[1];
    }
    float inv = 1.f / fmaxf(lsum, 1e-9f);
    float o0 = acc0 * inv, o1 = acc1 * inv;
    size_t base = (size_t)v * HD + h * 128 + lane * 2;
    if (res) {
        half2v r2 = *(const half2v*)&res[base];
        o0 += (float)r2[0]; o1 += (float)r2[1];
    }
    o0 += bias[h * 128 + lane * 2];
    o1 += bias[h * 128 + lane * 2 + 1];
    if (act_elu) {
        o0 = (o0 > 0.f) ? o0 : expm1f(o0);
        o1 = (o1 > 0.f) ? o1 : expm1f(o1);
    }
    if (out16) {
        half2v o; o[0] = (f16)o0; o[1] = (f16)o1;
        *(half2v*)&out16[base] = o;
    }
    if (out32) {
        out32[base] = o0;
        out32[base + 1] = o1;
    }
}

// ------------------------- head-mean + graph pooling -----------------------

__global__ void mean_pool_kernel(const float* __restrict__ x3,
                                 const int* __restrict__ gid,
                                 float* __restrict__ local,
                                 float* __restrict__ pooled,
                                 float* __restrict__ cnt) {
    int v = blockIdx.x;
    int d = threadIdx.x;
    const float* p = x3 + (size_t)v * 768;
    float s = 0.f;
#pragma unroll
    for (int h = 0; h < 6; ++h) s += p[h * 128 + d];
    s *= (1.f / 6.f);
    local[(size_t)v * 128 + d] = s;
    int g = gid[v];
    atomicAdd(&pooled[g * 128 + d], s);
    if (d == 0) atomicAdd(&cnt[g], 1.0f);
}

__global__ void final_mlp_kernel(const float* __restrict__ pooled,
                                 const float* __restrict__ cnt,
                                 const float* __restrict__ Wm,
                                 const float* __restrict__ bm,
                                 float* __restrict__ gout) {
    int g = blockIdx.x;
    int j = threadIdx.x;
    __shared__ float p[128];
    float c = fmaxf(cnt[g], 1.0f);
    p[j] = pooled[g * 128 + j] / c;
    __syncthreads();
    float s = 0.f;
#pragma unroll 16
    for (int k = 0; k < 128; ++k) s += p[k] * Wm[k * 128 + j];
    gout[g * 128 + j] = s + bm[j];
}

// --------------------------------- driver ----------------------------------

extern "C" void kernel_launch(void* const* d_in, const int* in_sizes, int n_in,
                              void* d_out, int out_size, void* d_ws, size_t ws_size,
                              hipStream_t stream) {
    const float* h     = (const float*)d_in[0];
    const int*   src   = (const int*)d_in[2];
    const int*   dst   = (const int*)d_in[3];
    const int*   gid   = (const int*)d_in[4];
    const float* W0    = (const float*)d_in[5];
    const float* al0   = (const float*)d_in[6];
    const float* ar0   = (const float*)d_in[7];
    const float* b0    = (const float*)d_in[8];
    const float* W1    = (const float*)d_in[9];
    const float* al1   = (const float*)d_in[10];
    const float* ar1   = (const float*)d_in[11];
    const float* b1    = (const float*)d_in[12];
    const float* W2    = (const float*)d_in[13];
    const float* al2   = (const float*)d_in[14];
    const float* ar2   = (const float*)d_in[15];
    const float* b2    = (const float*)d_in[16];
    const float* resW2 = (const float*)d_in[17];
    const float* Wm    = (const float*)d_in[18];
    const float* bm    = (const float*)d_in[19];

    const int n = in_sizes[0] / 128;   // 20000
    const int E = in_sizes[2];         // 320000

    size_t off = 0;
    auto take = [&](size_t bytes) -> void* {
        void* p = (char*)d_ws + off;
        off = (off + bytes + 255) & ~(size_t)255;
        return p;
    };
    f16* h16     = (f16*)take((size_t)M_PAD * 128 * 2);
    f16* Wt0     = (f16*)take((size_t)512 * 128 * 2);
    f16* Wt1     = (f16*)take((size_t)512 * 512 * 2);
    f16* Wt2     = (f16*)take((size_t)768 * 512 * 2);
    f16* resWt2  = (f16*)take((size_t)768 * 512 * 2);
    f16* feat16  = (f16*)take((size_t)M_PAD * 768 * 2);  // per-layer fc output
    f16* res2_16 = (f16*)take((size_t)M_PAD * 768 * 2);  // x2 @ resW2
    f16* x1_16   = (f16*)take((size_t)M_PAD * 512 * 2);
    f16* x2_16   = (f16*)take((size_t)M_PAD * 512 * 2);
    float* x3    = (float*)take((size_t)n * 768 * 4);
    float* el    = (float*)take((size_t)n * 6 * 4);
    float* er    = (float*)take((size_t)n * 6 * 4);
    int* deg     = (int*)take((size_t)n * 4);
    int* row_off = (int*)take((size_t)(n + 1) * 4);
    int* fillc   = (int*)take((size_t)n * 4);
    int* csr_src = (int*)take((size_t)E * 4);
    float* pooled = (float*)take(64 * 128 * 4);
    float* cnt    = (float*)take(64 * 4);

    float* out_local  = (float*)d_out;
    float* out_global = (float*)d_out + (size_t)n * 128;

    // --- init / converts / CSR ---
    hipMemsetAsync(deg, 0, (size_t)n * 4, stream);
    hipMemsetAsync(fillc, 0, (size_t)n * 4, stream);
    hipMemsetAsync(pooled, 0, 64 * 128 * 4, stream);
    hipMemsetAsync(cnt, 0, 64 * 4, stream);
    // zero pad rows of activation buffers (GEMM A-inputs must be 0 in pad)
    hipMemsetAsync(x1_16 + (size_t)n * 512, 0, (size_t)(M_PAD - n) * 512 * 2, stream);
    hipMemsetAsync(x2_16 + (size_t)n * 512, 0, (size_t)(M_PAD - n) * 512 * 2, stream);

    {
        long nv = (long)n * 128, nt = (long)M_PAD * 128;
        cvt_pad_kernel<<<(int)((nt / 4 + 255) / 256), 256, 0, stream>>>(h, h16, nv, nt);
    }
    transpose_cvt_kernel<<<dim3(512 / 32, 128 / 32), dim3(32, 8), 0, stream>>>(W0, Wt0, 128, 512);
    transpose_cvt_kernel<<<dim3(512 / 32, 512 / 32), dim3(32, 8), 0, stream>>>(W1, Wt1, 512, 512);
    transpose_cvt_kernel<<<dim3(768 / 32, 512 / 32), dim3(32, 8), 0, stream>>>(W2, Wt2, 512, 768);
    transpose_cvt_kernel<<<dim3(768 / 32, 512 / 32), dim3(32, 8), 0, stream>>>(resW2, resWt2, 512, 768);

    deg_kernel<<<(E + 255) / 256, 256, 0, stream>>>(dst, deg, E);
    scan_kernel<<<1, 1024, 0, stream>>>(deg, row_off, n);
    fill_kernel<<<(E + 255) / 256, 256, 0, stream>>>(src, dst, row_off, fillc, csr_src, E);

    const int gy = M_PAD / 128;   // 157

    // --- layer 0: feat = h16 @ W0, H=4, no res, elu ---
    gemm16_kernel<<<dim3(512 / 128, gy), 256, 0, stream>>>(h16, Wt0, feat16, 512, 128);
    attn_logits_kernel<<<n, dim3(64, 4), 0, stream>>>(feat16, al0, ar0, el, er, 4);
    gat_aggregate_kernel<<<n, dim3(64, 4), 0, stream>>>(feat16, el, er, row_off, csr_src,
                                                        nullptr, b0, x1_16, nullptr, 4, 1);
    // --- layer 1: feat = x1 @ W1, H=4, identity res, elu ---
    gemm16_kernel<<<dim3(512 / 128, gy), 256, 0, stream>>>(x1_16, Wt1, feat16, 512, 512);
    attn_logits_kernel<<<n, dim3(64, 4), 0, stream>>>(feat16, al1, ar1, el, er, 4);
    gat_aggregate_kernel<<<n, dim3(64, 4), 0, stream>>>(feat16, el, er, row_off, csr_src,
                                                        x1_16, b1, x2_16, nullptr, 4, 1);
    // --- layer 2: feat = x2 @ W2, res2 = x2 @ resW2, H=6, no act ---
    gemm16_kernel<<<dim3(768 / 128, gy), 256, 0, stream>>>(x2_16, Wt2, feat16, 768, 512);
    gemm16_kernel<<<dim3(768 / 128, gy), 256, 0, stream>>>(x2_16, resWt2, res2_16, 768, 512);
    attn_logits_kernel<<<n, dim3(64, 6), 0, stream>>>(feat16, al2, ar2, el, er, 6);
    gat_aggregate_kernel<<<n, dim3(64, 6), 0, stream>>>(feat16, el, er, row_off, csr_src,
                                                        res2_16, b2, nullptr, x3, 6, 0);
    // --- head mean + pooling + final MLP ---
    mean_pool_kernel<<<n, 128, 0, stream>>>(x3, gid, out_local, pooled, cnt);
    final_mlp_kernel<<<64, 128, 0, stream>>>(pooled, cnt, Wm, bm, out_global);
}

// Round 3
// 667.935 us; speedup vs baseline: 2.1781x; 1.4806x over previous
//
#include <hip/hip_runtime.h>
#include <math.h>

// ---------------------------------------------------------------------------
// GAT 3-layer + pooling.
//  - GEMMs: fp16 MFMA (16x16x32), 128x128x32 tiles, global_load_lds staging.
//  - Aggregation: one wave per node, ALL heads fused (lane owns 2H channels).
//    Per 64-edge chunk: edge-parallel phase computes exp-weights into LDS
//    (no max subtraction -- softmax is shift-invariant, logits are O(5)),
//    channel-parallel phase does broadcast LDS reads + one contiguous
//    feat-row gather per edge. Head-mean + graph pooling fused into the
//    layer-2 epilogue via LDS transpose.
// ---------------------------------------------------------------------------

typedef _Float16 f16;
typedef __attribute__((ext_vector_type(8))) _Float16 half8;
typedef __attribute__((ext_vector_type(4))) _Float16 half4;
typedef __attribute__((ext_vector_type(2))) _Float16 half2v;
typedef __attribute__((ext_vector_type(4))) float float4v;

#define M_PAD 20096   // 20000 rounded up to 128

__device__ inline void gload_lds16(const void* g, void* l) {
    __builtin_amdgcn_global_load_lds((const __attribute__((address_space(1))) unsigned*)g,
                                     (__attribute__((address_space(3))) unsigned*)l,
                                     16, 0, 0);
}

// ----------------------------- CSR construction ---------------------------

__global__ __launch_bounds__(256) void deg_kernel(const int* __restrict__ dst,
                                                  int* __restrict__ deg, int E) {
    int e = blockIdx.x * 256 + threadIdx.x;
    if (e < E) atomicAdd(&deg[dst[e]], 1);
}

__global__ __launch_bounds__(1024) void scan_kernel(const int* __restrict__ deg,
                                                    int* __restrict__ row_off, int n) {
    __shared__ int sums[1024];
    int t = threadIdx.x;
    int CH = (n + 1023) >> 10;
    int base = t * CH;
    int s = 0;
    for (int i = 0; i < CH; ++i) { int idx = base + i; if (idx < n) s += deg[idx]; }
    sums[t] = s;
    __syncthreads();
    for (int off = 1; off < 1024; off <<= 1) {
        int v = (t >= off) ? sums[t - off] : 0;
        __syncthreads();
        sums[t] += v;
        __syncthreads();
    }
    int run = (t == 0) ? 0 : sums[t - 1];
    for (int i = 0; i < CH; ++i) {
        int idx = base + i;
        if (idx < n) { row_off[idx] = run; run += deg[idx]; }
    }
    if (t == 1023) row_off[n] = run;
}

__global__ __launch_bounds__(256) void fill_kernel(const int* __restrict__ src,
                                                   const int* __restrict__ dst,
                                                   const int* __restrict__ row_off,
                                                   int* __restrict__ fill,
                                                   int* __restrict__ csr_src, int E) {
    int e = blockIdx.x * 256 + threadIdx.x;
    if (e < E) {
        int d = dst[e];
        int pos = row_off[d] + atomicAdd(&fill[d], 1);
        csr_src[pos] = src[e];
    }
}

// ------------------------------ converts -----------------------------------

__global__ __launch_bounds__(256) void cvt_pad_kernel(const float* __restrict__ x,
                                                      f16* __restrict__ y,
                                                      long n_valid, long n_total) {
    long i = ((long)blockIdx.x * 256 + threadIdx.x) * 4;
    if (i >= n_total) return;
    float4 v = make_float4(0.f, 0.f, 0.f, 0.f);
    if (i < n_valid) v = *(const float4*)&x[i];
    half4 o; o[0] = (f16)v.x; o[1] = (f16)v.y; o[2] = (f16)v.z; o[3] = (f16)v.w;
    *(half4*)&y[i] = o;
}

// Wt[n][k] = (f16) W[k][n].  K,N multiples of 32.  block (32,8)
__global__ __launch_bounds__(256) void transpose_cvt_kernel(const float* __restrict__ W,
                                                            f16* __restrict__ Wt,
                                                            int K, int N) {
    __shared__ float tile[32][33];
    int n0 = blockIdx.x * 32, k0 = blockIdx.y * 32;
    int tx = threadIdx.x, ty = threadIdx.y;
#pragma unroll
    for (int i = 0; i < 32; i += 8)
        tile[ty + i][tx] = W[(size_t)(k0 + ty + i) * N + n0 + tx];
    __syncthreads();
#pragma unroll
    for (int i = 0; i < 32; i += 8)
        Wt[(size_t)(n0 + ty + i) * K + k0 + tx] = (f16)tile[tx][ty + i];
}

// ------------------------------ fp16 MFMA GEMM -----------------------------

__global__ __launch_bounds__(256) void gemm16_kernel(const f16* __restrict__ A,
                                                     const f16* __restrict__ Bt,
                                                     f16* __restrict__ C,
                                                     int N, int K) {
    __shared__ f16 As[128 * 32];
    __shared__ f16 Bs[128 * 32];
    int t = threadIdx.x;
    int w = t >> 6;
    int l = t & 63;
    size_t bm = (size_t)blockIdx.y * 128;
    int bn = blockIdx.x * 128;
    int wm = (w & 1) * 64;
    int wn = (w >> 1) * 64;

    int srow = t >> 2;
    int scol = (t & 3) * 8;
    const f16* ag0 = A + (bm + srow) * K + scol;
    const f16* ag1 = A + (bm + 64 + srow) * K + scol;
    const f16* bg0 = Bt + (size_t)(bn + srow) * K + scol;
    const f16* bg1 = Bt + (size_t)(bn + 64 + srow) * K + scol;
    f16* al0 = As + t * 8;
    f16* al1 = As + 2048 + t * 8;
    f16* bl0 = Bs + t * 8;
    f16* bl1 = Bs + 2048 + t * 8;

    float4v acc[4][4];
#pragma unroll
    for (int i = 0; i < 4; ++i)
#pragma unroll
        for (int j = 0; j < 4; ++j) acc[i][j] = (float4v)(0.f);

    int ml = l & 15, q = l >> 4;
    const f16* ap = As + (wm + ml) * 32 + q * 8;
    const f16* bp = Bs + (wn + ml) * 32 + q * 8;

    for (int k0 = 0; k0 < K; k0 += 32) {
        gload_lds16(ag0 + k0, al0);
        gload_lds16(ag1 + k0, al1);
        gload_lds16(bg0 + k0, bl0);
        gload_lds16(bg1 + k0, bl1);
        __syncthreads();
        half8 af[4], bf[4];
#pragma unroll
        for (int mt = 0; mt < 4; ++mt) af[mt] = *(const half8*)(ap + mt * 16 * 32);
#pragma unroll
        for (int nt = 0; nt < 4; ++nt) bf[nt] = *(const half8*)(bp + nt * 16 * 32);
#pragma unroll
        for (int mt = 0; mt < 4; ++mt)
#pragma unroll
            for (int nt = 0; nt < 4; ++nt)
                acc[mt][nt] = __builtin_amdgcn_mfma_f32_16x16x32_f16(bf[nt], af[mt],
                                                                     acc[mt][nt], 0, 0, 0);
        __syncthreads();
    }
#pragma unroll
    for (int mt = 0; mt < 4; ++mt) {
        size_t row = bm + wm + mt * 16 + ml;
#pragma unroll
        for (int nt = 0; nt < 4; ++nt) {
            half4 hv;
#pragma unroll
            for (int r = 0; r < 4; ++r) hv[r] = (f16)acc[mt][nt][r];
            *(half4*)&C[row * N + bn + wn + nt * 16 + q * 4] = hv;
        }
    }
}

// --------------------------- attention logits ------------------------------
// writes el8/er8 with node-stride 8 (so aggregate can vector-load)

__global__ void attn_logits_kernel(const f16* __restrict__ feat,
                                   const float* __restrict__ al,
                                   const float* __restrict__ ar,
                                   float* __restrict__ el8, float* __restrict__ er8,
                                   int H) {
    int v = blockIdx.x;
    int h = threadIdx.y;
    int lane = threadIdx.x;
    half2v f2 = *(const half2v*)&feat[(size_t)v * H * 128 + h * 128 + 2 * lane];
    float f0 = (float)f2[0], f1 = (float)f2[1];
    float sl = f0 * al[h * 128 + 2 * lane] + f1 * al[h * 128 + 2 * lane + 1];
    float sr = f0 * ar[h * 128 + 2 * lane] + f1 * ar[h * 128 + 2 * lane + 1];
#pragma unroll
    for (int off = 32; off > 0; off >>= 1) {
        sl += __shfl_down(sl, off, 64);
        sr += __shfl_down(sr, off, 64);
    }
    if (lane == 0) { el8[(size_t)v * 8 + h] = sl; er8[(size_t)v * 8 + h] = sr; }
}

// ------------------ head-fused aggregation, H=4 ----------------------------
// one wave per node; lane owns channels 8*lane .. 8*lane+7 (head = lane>>4)

__global__ __launch_bounds__(256) void gat_agg4_kernel(
        const f16* __restrict__ feat, const float* __restrict__ el8,
        const float* __restrict__ er8, const int* __restrict__ row_off,
        const int* __restrict__ csr_src, const f16* __restrict__ res,
        const float* __restrict__ bias, f16* __restrict__ out, int n) {
    __shared__ float wls[4][256];
    __shared__ int sls[4][64];
    int wid = threadIdx.x >> 6, lane = threadIdx.x & 63;
    int v = blockIdx.x * 4 + wid;
    if (v >= n) return;
    int hh = lane >> 4;
    float4 erv = *(const float4*)&er8[(size_t)v * 8];
    float era[4] = {erv.x, erv.y, erv.z, erv.w};
    int beg = row_off[v], end = row_off[v + 1];
    float acc[8] = {0.f, 0.f, 0.f, 0.f, 0.f, 0.f, 0.f, 0.f};
    float ls[4] = {0.f, 0.f, 0.f, 0.f};
    float* wl = wls[wid];
    int* sl = sls[wid];

    for (int pos = beg; pos < end; pos += 64) {
        int cnt = min(64, end - pos);
        // edge-parallel: lane grabs one edge, computes all-head weights
        int s_l = (lane < cnt) ? csr_src[pos + lane] : 0;
        float4 e4 = *(const float4*)&el8[(size_t)s_l * 8];
        float ee[4] = {e4.x, e4.y, e4.z, e4.w};
        float w4[4];
#pragma unroll
        for (int h = 0; h < 4; ++h) {
            float lg = ee[h] + era[h];
            lg = (lg >= 0.f) ? lg : 0.2f * lg;
            float w = __expf(lg);
            if (lane >= cnt) w = 0.f;
            w4[h] = w;
            ls[h] += w;
        }
        sl[lane] = s_l;
        *(float4*)&wl[lane * 4] = make_float4(w4[0], w4[1], w4[2], w4[3]);
        // channel-parallel: broadcast LDS reads + contiguous feat row gather
#pragma unroll 4
        for (int i = 0; i < cnt; ++i) {
            int s = sl[i];
            float w = wl[i * 4 + hh];
            half8 f = *(const half8*)&feat[(size_t)s * 512 + lane * 8];
#pragma unroll
            for (int j = 0; j < 8; ++j) acc[j] += w * (float)f[j];
        }
    }
#pragma unroll
    for (int h = 0; h < 4; ++h)
#pragma unroll
        for (int off = 32; off >= 1; off >>= 1) ls[h] += __shfl_xor(ls[h], off, 64);
    float lsh = ls[0];
    lsh = (hh == 1) ? ls[1] : lsh;
    lsh = (hh == 2) ? ls[2] : lsh;
    lsh = (hh == 3) ? ls[3] : lsh;
    float inv = 1.f / fmaxf(lsh, 1e-9f);
    int c0 = lane * 8;
    size_t base = (size_t)v * 512 + c0;
    float ox[8];
#pragma unroll
    for (int j = 0; j < 8; ++j) ox[j] = acc[j] * inv;
    if (res) {
        half8 r = *(const half8*)&res[base];
#pragma unroll
        for (int j = 0; j < 8; ++j) ox[j] += (float)r[j];
    }
    float4 bv0 = *(const float4*)&bias[c0];
    float4 bv1 = *(const float4*)&bias[c0 + 4];
    ox[0] += bv0.x; ox[1] += bv0.y; ox[2] += bv0.z; ox[3] += bv0.w;
    ox[4] += bv1.x; ox[5] += bv1.y; ox[6] += bv1.z; ox[7] += bv1.w;
    half8 o;
#pragma unroll
    for (int j = 0; j < 8; ++j) {
        float t = ox[j];
        t = (t > 0.f) ? t : expm1f(t);   // elu (both H=4 layers use it)
        o[j] = (f16)t;
    }
    *(half8*)&out[base] = o;
}

// ------------------ head-fused aggregation, H=6 ----------------------------
// one wave per node; lane owns channels 12*lane .. 12*lane+11 (3 groups of 4,
// each group within one head). Fused epilogue: residual+bias, head-mean via
// LDS transpose, local_feat store + graph-pool atomics.

__global__ __launch_bounds__(256) void gat_agg6_kernel(
        const f16* __restrict__ feat, const float* __restrict__ el8,
        const float* __restrict__ er8, const int* __restrict__ row_off,
        const int* __restrict__ csr_src, const f16* __restrict__ res,
        const float* __restrict__ bias, const int* __restrict__ gid,
        float* __restrict__ out_local, float* __restrict__ pooled,
        float* __restrict__ cntbuf, int n) {
    __shared__ float wls[4][64 * 6];
    __shared__ int sls[4][64];
    __shared__ float xbuf[4][768];
    int wid = threadIdx.x >> 6, lane = threadIdx.x & 63;
    int v = blockIdx.x * 4 + wid;
    if (v >= n) return;
    int c0 = lane * 12;
    int gh0 = c0 >> 7, gh1 = (c0 + 4) >> 7, gh2 = (c0 + 8) >> 7;
    float era[6];
    {
        float4 a = *(const float4*)&er8[(size_t)v * 8];
        float2 b = *(const float2*)&er8[(size_t)v * 8 + 4];
        era[0] = a.x; era[1] = a.y; era[2] = a.z; era[3] = a.w;
        era[4] = b.x; era[5] = b.y;
    }
    int beg = row_off[v], end = row_off[v + 1];
    float acc[12];
#pragma unroll
    for (int j = 0; j < 12; ++j) acc[j] = 0.f;
    float ls[6] = {0.f, 0.f, 0.f, 0.f, 0.f, 0.f};
    float* wl = wls[wid];
    int* sl = sls[wid];

    for (int pos = beg; pos < end; pos += 64) {
        int cnt = min(64, end - pos);
        int s_l = (lane < cnt) ? csr_src[pos + lane] : 0;
        float ee[6];
        {
            float4 a = *(const float4*)&el8[(size_t)s_l * 8];
            float2 b = *(const float2*)&el8[(size_t)s_l * 8 + 4];
            ee[0] = a.x; ee[1] = a.y; ee[2] = a.z; ee[3] = a.w;
            ee[4] = b.x; ee[5] = b.y;
        }
#pragma unroll
        for (int h = 0; h < 6; ++h) {
            float lg = ee[h] + era[h];
            lg = (lg >= 0.f) ? lg : 0.2f * lg;
            float w = __expf(lg);
            if (lane >= cnt) w = 0.f;
            wl[lane * 6 + h] = w;
            ls[h] += w;
        }
        sl[lane] = s_l;
#pragma unroll 4
        for (int i = 0; i < cnt; ++i) {
            int s = sl[i];
            float w0 = wl[i * 6 + gh0];
            float w1 = wl[i * 6 + gh1];
            float w2 = wl[i * 6 + gh2];
            const f16* fp = &feat[(size_t)s * 768 + c0];
            half4 f0 = *(const half4*)fp;
            half4 f1 = *(const half4*)(fp + 4);
            half4 f2 = *(const half4*)(fp + 8);
#pragma unroll
            for (int j = 0; j < 4; ++j) {
                acc[j]     += w0 * (float)f0[j];
                acc[4 + j] += w1 * (float)f1[j];
                acc[8 + j] += w2 * (float)f2[j];
            }
        }
    }
#pragma unroll
    for (int h = 0; h < 6; ++h)
#pragma unroll
        for (int off = 32; off >= 1; off >>= 1) ls[h] += __shfl_xor(ls[h], off, 64);
    auto pick6 = [&](int h) {
        float r = ls[0];
        r = (h == 1) ? ls[1] : r;
        r = (h == 2) ? ls[2] : r;
        r = (h == 3) ? ls[3] : r;
        r = (h == 4) ? ls[4] : r;
        r = (h == 5) ? ls[5] : r;
        return r;
    };
    float iv0 = 1.f / fmaxf(pick6(gh0), 1e-9f);
    float iv1 = 1.f / fmaxf(pick6(gh1), 1e-9f);
    float iv2 = 1.f / fmaxf(pick6(gh2), 1e-9f);
    size_t base = (size_t)v * 768 + c0;
    float ox[12];
#pragma unroll
    for (int j = 0; j < 4; ++j) {
        ox[j]     = acc[j] * iv0;
        ox[4 + j] = acc[4 + j] * iv1;
        ox[8 + j] = acc[8 + j] * iv2;
    }
    {   // residual (res2 = x2 @ resW2, fp16)
        half4 r0 = *(const half4*)&res[base];
        half4 r1 = *(const half4*)&res[base + 4];
        half4 r2 = *(const half4*)&res[base + 8];
#pragma unroll
        for (int j = 0; j < 4; ++j) {
            ox[j]     += (float)r0[j];
            ox[4 + j] += (float)r1[j];
            ox[8 + j] += (float)r2[j];
        }
    }
    float4 bv0 = *(const float4*)&bias[c0];
    float4 bv1 = *(const float4*)&bias[c0 + 4];
    float4 bv2 = *(const float4*)&bias[c0 + 8];
    ox[0] += bv0.x; ox[1]  += bv0.y; ox[2]  += bv0.z; ox[3]  += bv0.w;
    ox[4] += bv1.x; ox[5]  += bv1.y; ox[6]  += bv1.z; ox[7]  += bv1.w;
    ox[8] += bv2.x; ox[9]  += bv2.y; ox[10] += bv2.z; ox[11] += bv2.w;
    // no activation on layer 2; head-mean via LDS transpose
    float* xb = xbuf[wid];
    *(float4*)&xb[c0]     = make_float4(ox[0], ox[1], ox[2],  ox[3]);
    *(float4*)&xb[c0 + 4] = make_float4(ox[4], ox[5], ox[6],  ox[7]);
    *(float4*)&xb[c0 + 8] = make_float4(ox[8], ox[9], ox[10], ox[11]);
    int d0 = 2 * lane;
    float s0 = 0.f, s1 = 0.f;
#pragma unroll
    for (int hh = 0; hh < 6; ++hh) {
        s0 += xb[hh * 128 + d0];
        s1 += xb[hh * 128 + d0 + 1];
    }
    s0 *= (1.f / 6.f);
    s1 *= (1.f / 6.f);
    *(float2*)&out_local[(size_t)v * 128 + d0] = make_float2(s0, s1);
    int g = gid[v];
    atomicAdd(&pooled[g * 128 + d0], s0);
    atomicAdd(&pooled[g * 128 + d0 + 1], s1);
    if (lane == 0) atomicAdd(&cntbuf[g], 1.0f);
}

// ------------------------------ final MLP ----------------------------------

__global__ void final_mlp_kernel(const float* __restrict__ pooled,
                                 const float* __restrict__ cnt,
                                 const float* __restrict__ Wm,
                                 const float* __restrict__ bm,
                                 float* __restrict__ gout) {
    int g = blockIdx.x;
    int j = threadIdx.x;
    __shared__ float p[128];
    float c = fmaxf(cnt[g], 1.0f);
    p[j] = pooled[g * 128 + j] / c;
    __syncthreads();
    float s = 0.f;
#pragma unroll 16
    for (int k = 0; k < 128; ++k) s += p[k] * Wm[k * 128 + j];
    gout[g * 128 + j] = s + bm[j];
}

// --------------------------------- driver ----------------------------------

extern "C" void kernel_launch(void* const* d_in, const int* in_sizes, int n_in,
                              void* d_out, int out_size, void* d_ws, size_t ws_size,
                              hipStream_t stream) {
    const float* h     = (const float*)d_in[0];
    const int*   src   = (const int*)d_in[2];
    const int*   dst   = (const int*)d_in[3];
    const int*   gid   = (const int*)d_in[4];
    const float* W0    = (const float*)d_in[5];
    const float* al0   = (const float*)d_in[6];
    const float* ar0   = (const float*)d_in[7];
    const float* b0    = (const float*)d_in[8];
    const float* W1    = (const float*)d_in[9];
    const float* al1   = (const float*)d_in[10];
    const float* ar1   = (const float*)d_in[11];
    const float* b1    = (const float*)d_in[12];
    const float* W2    = (const float*)d_in[13];
    const float* al2   = (const float*)d_in[14];
    const float* ar2   = (const float*)d_in[15];
    const float* b2    = (const float*)d_in[16];
    const float* resW2 = (const float*)d_in[17];
    const float* Wm    = (const float*)d_in[18];
    const float* bm    = (const float*)d_in[19];

    const int n = in_sizes[0] / 128;   // 20000
    const int E = in_sizes[2];         // 320000

    size_t off = 0;
    auto take = [&](size_t bytes) -> void* {
        void* p = (char*)d_ws + off;
        off = (off + bytes + 255) & ~(size_t)255;
        return p;
    };
    f16* h16     = (f16*)take((size_t)M_PAD * 128 * 2);
    f16* Wt0     = (f16*)take((size_t)512 * 128 * 2);
    f16* Wt1     = (f16*)take((size_t)512 * 512 * 2);
    f16* Wt2     = (f16*)take((size_t)768 * 512 * 2);
    f16* resWt2  = (f16*)take((size_t)768 * 512 * 2);
    f16* feat16  = (f16*)take((size_t)M_PAD * 768 * 2);
    f16* res2_16 = (f16*)take((size_t)M_PAD * 768 * 2);
    f16* x1_16   = (f16*)take((size_t)M_PAD * 512 * 2);
    f16* x2_16   = (f16*)take((size_t)M_PAD * 512 * 2);
    float* el8   = (float*)take((size_t)n * 8 * 4);
    float* er8   = (float*)take((size_t)n * 8 * 4);
    int* deg     = (int*)take((size_t)n * 4);
    int* row_off = (int*)take((size_t)(n + 1) * 4);
    int* fillc   = (int*)take((size_t)n * 4);
    int* csr_src = (int*)take((size_t)E * 4);
    float* pooled = (float*)take(64 * 128 * 4);
    float* cnt    = (float*)take(64 * 4);

    float* out_local  = (float*)d_out;
    float* out_global = (float*)d_out + (size_t)n * 128;

    hipMemsetAsync(deg, 0, (size_t)n * 4, stream);
    hipMemsetAsync(fillc, 0, (size_t)n * 4, stream);
    hipMemsetAsync(pooled, 0, 64 * 128 * 4, stream);
    hipMemsetAsync(cnt, 0, 64 * 4, stream);
    hipMemsetAsync(x1_16 + (size_t)n * 512, 0, (size_t)(M_PAD - n) * 512 * 2, stream);
    hipMemsetAsync(x2_16 + (size_t)n * 512, 0, (size_t)(M_PAD - n) * 512 * 2, stream);

    {
        long nv = (long)n * 128, nt = (long)M_PAD * 128;
        cvt_pad_kernel<<<(int)((nt / 4 + 255) / 256), 256, 0, stream>>>(h, h16, nv, nt);
    }
    transpose_cvt_kernel<<<dim3(512 / 32, 128 / 32), dim3(32, 8), 0, stream>>>(W0, Wt0, 128, 512);
    transpose_cvt_kernel<<<dim3(512 / 32, 512 / 32), dim3(32, 8), 0, stream>>>(W1, Wt1, 512, 512);
    transpose_cvt_kernel<<<dim3(768 / 32, 512 / 32), dim3(32, 8), 0, stream>>>(W2, Wt2, 512, 768);
    transpose_cvt_kernel<<<dim3(768 / 32, 512 / 32), dim3(32, 8), 0, stream>>>(resW2, resWt2, 512, 768);

    deg_kernel<<<(E + 255) / 256, 256, 0, stream>>>(dst, deg, E);
    scan_kernel<<<1, 1024, 0, stream>>>(deg, row_off, n);
    fill_kernel<<<(E + 255) / 256, 256, 0, stream>>>(src, dst, row_off, fillc, csr_src, E);

    const int gy = M_PAD / 128;
    const int gagg = (n + 3) / 4;

    // --- layer 0 ---
    gemm16_kernel<<<dim3(512 / 128, gy), 256, 0, stream>>>(h16, Wt0, feat16, 512, 128);
    attn_logits_kernel<<<n, dim3(64, 4), 0, stream>>>(feat16, al0, ar0, el8, er8, 4);
    gat_agg4_kernel<<<gagg, 256, 0, stream>>>(feat16, el8, er8, row_off, csr_src,
                                              nullptr, b0, x1_16, n);
    // --- layer 1 ---
    gemm16_kernel<<<dim3(512 / 128, gy), 256, 0, stream>>>(x1_16, Wt1, feat16, 512, 512);
    attn_logits_kernel<<<n, dim3(64, 4), 0, stream>>>(feat16, al1, ar1, el8, er8, 4);
    gat_agg4_kernel<<<gagg, 256, 0, stream>>>(feat16, el8, er8, row_off, csr_src,
                                              x1_16, b1, x2_16, n);
    // --- layer 2 ---
    gemm16_kernel<<<dim3(768 / 128, gy), 256, 0, stream>>>(x2_16, Wt2, feat16, 768, 512);
    gemm16_kernel<<<dim3(768 / 128, gy), 256, 0, stream>>>(x2_16, resWt2, res2_16, 768, 512);
    attn_logits_kernel<<<n, dim3(64, 6), 0, stream>>>(feat16, al2, ar2, el8, er8, 6);
    gat_agg6_kernel<<<gagg, 256, 0, stream>>>(feat16, el8, er8, row_off, csr_src,
                                              res2_16, b2, gid, out_local, pooled, cnt, n);
    // --- pooling epilogue ---
    final_mlp_kernel<<<64, 128, 0, stream>>>(pooled, cnt, Wm, bm, out_global);
}